// Round 10
// baseline (374.080 us; speedup 1.0000x reference)
//
#include <hip/hip_runtime.h>
#include <hip/hip_bf16.h>
#include <cstdint>
#include <cstddef>

#define TOK   8192
#define DIN   4096
#define DOUT  4096
#define RANK  16
#define KE    4160   // DIN + 16 (loraB) + 1 (bias) + 47 pad -> 65 * 64
#define NKT64 (KE / 64)

#define BM 256
#define BN 256

// prep_fused block ranges
#define PXB 512                    // prep_x blocks
#define DQB 8192                   // dequant blocks
#define TLB 16                     // tail blocks

typedef __attribute__((ext_vector_type(8))) short bf16x8;
typedef __attribute__((ext_vector_type(4))) float f32x4;
typedef __attribute__((ext_vector_type(4))) int i32x4;
typedef __attribute__((ext_vector_type(8))) unsigned short u16x8;

__device__ __constant__ float NF4_CODE_D[16] = {
    -1.0f, -0.6961928009986877f, -0.5250730514526367f, -0.39491748809814453f,
    -0.28444138169288635f, -0.18477343022823334f, -0.09105003625154495f, 0.0f,
    0.07958029955625534f, 0.16093020141124725f, 0.24611230194568634f,
    0.33791524171829224f, 0.44070982933044434f, 0.5626170039176941f,
    0.7229568362236023f, 1.0f};

__device__ __forceinline__ unsigned short f2bf(float f) {
    union { float f; unsigned u; } v; v.f = f;
    unsigned u = v.u;
    unsigned r = (u + 0x7FFFu + ((u >> 16) & 1u)) >> 16;  // round-nearest-even
    return (unsigned short)r;
}

__device__ __forceinline__ void async_copy16(const void* g, void* l) {
    __builtin_amdgcn_global_load_lds(
        (const __attribute__((address_space(1))) void*)g,
        (__attribute__((address_space(3))) void*)l,
        16, 0, 0);
}

// ---------------------------------------------------------------------------
// Fused prep: one launch, three block ranges.
//  [0, PXB):        x -> bf16 xe[TOK][KE]; cols [4096,4112)=4*(x@lora_A);
//                   col 4112 = 1.0; rest 0.   (16B stores: 8 k per lane)
//  [PXB, PXB+DQB):  NF4 dequant -> we[DOUT][KE] cols [0,4096)
//  [PXB+DQB, +TLB): we tail cols: loraB^T, bias, zeros
// Cache hygiene: x and codes are read-once -> NONTEMPORAL loads, so the
// xe/we stores (reused by the gemm) stay L3-resident.
// ---------------------------------------------------------------------------
__global__ __launch_bounds__(256) void prep_fused(
        const float* __restrict__ x, const float* __restrict__ lora_A,
        const int* __restrict__ codes, const float* __restrict__ absmax,
        const float* __restrict__ bias, const float* __restrict__ lora_B,
        unsigned short* __restrict__ xe, unsigned short* __restrict__ we) {
    __shared__ float tab[16];
    const int bid = blockIdx.x;
    const int tid = threadIdx.x;

    if (bid < PXB) {
        // ---- prep_x: wave handles 4 tokens; lane covers 8 consecutive k ----
        const int l = tid & 63;
        const int w = tid >> 6;
        const int t0 = bid * 16 + w * 4;

        float p[4][16];
#pragma unroll
        for (int a = 0; a < 4; ++a)
#pragma unroll
            for (int r = 0; r < 16; ++r) p[a][r] = 0.f;

        for (int it = 0; it < 8; ++it) {
            const int kb = it * 512 + l * 8;
            f32x4 xv[4][2];
#pragma unroll
            for (int a = 0; a < 4; ++a) {
                const f32x4* xp = (const f32x4*)(x + (size_t)(t0 + a) * DIN + kb);
                xv[a][0] = __builtin_nontemporal_load(xp);
                xv[a][1] = __builtin_nontemporal_load(xp + 1);
            }
#pragma unroll
            for (int a = 0; a < 4; ++a) {
                u16x8 s;
#pragma unroll
                for (int h = 0; h < 2; ++h) {
                    s[h * 4 + 0] = f2bf(xv[a][h].x);
                    s[h * 4 + 1] = f2bf(xv[a][h].y);
                    s[h * 4 + 2] = f2bf(xv[a][h].z);
                    s[h * 4 + 3] = f2bf(xv[a][h].w);
                }
                *(u16x8*)(xe + (size_t)(t0 + a) * KE + kb) = s;  // 16B store
            }
#pragma unroll
            for (int j = 0; j < 8; ++j) {
                const float4* ap = (const float4*)(lora_A + (size_t)(kb + j) * RANK);
                const float4 a0 = ap[0], a1 = ap[1], a2 = ap[2], a3 = ap[3];
                const float av[16] = {a0.x, a0.y, a0.z, a0.w, a1.x, a1.y, a1.z, a1.w,
                                      a2.x, a2.y, a2.z, a2.w, a3.x, a3.y, a3.z, a3.w};
#pragma unroll
                for (int a = 0; a < 4; ++a) {
                    const f32x4 xh = xv[a][j >> 2];
                    const float xs = (j & 3) == 0 ? xh.x : (j & 3) == 1 ? xh.y
                                   : (j & 3) == 2 ? xh.z : xh.w;
#pragma unroll
                    for (int r = 0; r < 16; ++r) p[a][r] += xs * av[r];
                }
            }
        }

#pragma unroll
        for (int a = 0; a < 4; ++a) {
#pragma unroll
            for (int r = 0; r < 16; ++r) {
                float v = p[a][r];
#pragma unroll
                for (int off = 32; off > 0; off >>= 1) v += __shfl_xor(v, off, 64);
                if (l == r)
                    xe[(size_t)(t0 + a) * KE + DIN + r] = f2bf(4.0f * v);  // SCALING=4
            }
            if (l >= 16)  // cols 4112..4159: bias-one then zeros
                xe[(size_t)(t0 + a) * KE + DIN + l] =
                    (l == 16) ? (unsigned short)0x3F80u : (unsigned short)0u;
        }
    } else if (bid < PXB + DQB) {
        // ---- dequant_w ----
        if (tid < 16) tab[tid] = NF4_CODE_D[tid];
        __syncthreads();
        const size_t t = (size_t)(bid - PXB) * 256 + tid;
        const size_t base = t * 8;
        const int o = (int)(base >> 12);          // / DIN
        const int k = (int)(base & (DIN - 1));
        const float am = absmax[base >> 6];
        const i32x4 c0 = __builtin_nontemporal_load((const i32x4*)(codes + base));
        const i32x4 c1 = __builtin_nontemporal_load((const i32x4*)(codes + base + 4));
        u16x8 ov;
        ov[0] = f2bf(tab[c0.x] * am);
        ov[1] = f2bf(tab[c0.y] * am);
        ov[2] = f2bf(tab[c0.z] * am);
        ov[3] = f2bf(tab[c0.w] * am);
        ov[4] = f2bf(tab[c1.x] * am);
        ov[5] = f2bf(tab[c1.y] * am);
        ov[6] = f2bf(tab[c1.z] * am);
        ov[7] = f2bf(tab[c1.w] * am);
        *(u16x8*)(we + (size_t)o * KE + k) = ov;
    } else {
        // ---- fill we tail ----
        const int o = (bid - PXB - DQB) * 256 + tid;
        unsigned short* dst = we + (size_t)o * KE + DIN;
#pragma unroll
        for (int r = 0; r < RANK; ++r) dst[r] = f2bf(lora_B[(size_t)r * DOUT + o]);
        dst[16] = f2bf(bias[o]);
#pragma unroll
        for (int r = 17; r < 64; ++r) dst[r] = 0;
    }
}

// ---------------------------------------------------------------------------
// Kernel 2: C[t,o] = sum_k A[t,k]*B[o,k]  (K-major bf16, K=KE)
// R10 gemm = R4 schedule (best measured) + NONTEMPORAL C stores (the 134 MB
// write-once out-stream no longer evicts the reused A/B panels from L3).
// One-phase-ahead ds_read pipelining; staggered staging A/B/A/B; counted
// lgkm via compiler; 2 barriers + 2 counted vmcnt per K64-tile.
// vmcnt ledger (per wave; 2 loads per stageA/stageB):
//   ph1-top: outstanding {A(t,1),B(t,1),A(t+1,0)}=6 -> vmcnt(2) retires S1(t)
//            (last tile: {A(L,1),B(L,1)}=4 -> vmcnt(0))
//   ph3-top: outstanding {A(t+1,0),B(t+1,0),A(t+1,1)}=6 -> vmcnt(2) retires
//            S0(t+1)
// WAR: slot reuse distance 4 phases; overwriting stage follows a barrier
// postdating all readers' counted-lgkm retirement. Publication: reads of a
// newly staged slice occur only after its vmcnt+barrier.
// ---------------------------------------------------------------------------
__global__ __launch_bounds__(512, 2) void gemm_bt(const unsigned short* __restrict__ A,
                                                  const unsigned short* __restrict__ B,
                                                  float* __restrict__ C) {
    __shared__ __attribute__((aligned(1024))) char smem[4 * 32768];  // 128 KiB

    const int tid = threadIdx.x;
    const int l = tid & 63;
    const int w = tid >> 6;
    const int wm = w >> 2;      // 0..1
    const int wn = w & 3;       // 0..3

    const int tm = blockIdx.x >> 4;     // 32 row tiles
    const int tn = blockIdx.x & 15;     // 16 col tiles
    const int rowBase = tm * BM;
    const int colBase = tn * BN;

    // staging coords (pre-swizzled global source; linear LDS dest)
    int srow[2], scolb[2], loffs[2];
#pragma unroll
    for (int g = 0; g < 2; ++g) {
        const int loff = g * 8192 + tid * 16;               // linear LDS byte
        const int soff = loff ^ (((loff >> 7) & 7) << 4);   // involution
        loffs[g] = loff;
        srow[g] = soff >> 6;          // row of [256][32] bf16 slice
        scolb[g] = soff & 63;         // byte within 64B row
    }

    auto stageA = [&](int tt, int kh, int slot) {
        char* dst = smem + slot * 32768;
        const int k0 = tt * 64 + kh * 32;
#pragma unroll
        for (int g = 0; g < 2; ++g)
            async_copy16((const char*)A + ((size_t)(rowBase + srow[g]) * KE + k0) * 2 + scolb[g],
                         dst + loffs[g]);
    };
    auto stageB = [&](int tt, int kh, int slot) {
        char* dst = smem + slot * 32768 + 16384;
        const int k0 = tt * 64 + kh * 32;
#pragma unroll
        for (int g = 0; g < 2; ++g)
            async_copy16((const char*)B + ((size_t)(colBase + srow[g]) * KE + k0) * 2 + scolb[g],
                         dst + loffs[g]);
    };

    // swizzled fragment read offsets (within a 16 KiB slice)
    const int lmask = ((l >> 1) & 7) << 4;
    const int aoff = (((wm * 128 + (l & 15)) * 64) + ((l >> 4) * 16)) ^ lmask;
    const int boff = (((wn * 64 + (l & 15)) * 64) + ((l >> 4) * 16)) ^ lmask;

    f32x4 acc[8][4];
#pragma unroll
    for (int m = 0; m < 8; ++m)
#pragma unroll
        for (int n = 0; n < 4; ++n) acc[m][n] = (f32x4){0.f, 0.f, 0.f, 0.f};

    bf16x8 aLo[4], aHi[4], aLo2[4], aHi2[4], bCur[4], bNxt[4];

    // prologue: tile 0 slices into slots 0,1; publish S0(0); preload ph0 regs
    stageA(0, 0, 0); stageB(0, 0, 0);
    stageA(0, 1, 1); stageB(0, 1, 1);
    asm volatile("s_waitcnt vmcnt(4)" ::: "memory");
    __builtin_amdgcn_s_barrier();
    {
        const char* S0 = smem;  // slot 0
#pragma unroll
        for (int n = 0; n < 4; ++n)
            bCur[n] = *(const bf16x8*)(S0 + 16384 + boff + n * 1024);
#pragma unroll
        for (int m = 0; m < 4; ++m)
            aLo[m] = *(const bf16x8*)(S0 + aoff + m * 1024);
    }

    for (int t = 0; t < NKT64; ++t) {
        const char* S0 = smem + ((2 * t) & 3) * 32768;       // slice (t,k0)
        const char* S1 = smem + ((2 * t + 1) & 3) * 32768;   // slice (t,k1)
        const char* Sn = smem + ((2 * t + 2) & 3) * 32768;   // slice (t+1,k0)
        const int d0 = (2 * t + 2) & 3, d1 = (2 * t + 3) & 3;
        const bool more = (t + 1 < NKT64);

        // ---- phase 0: MFMA(aLo x bCur); read-ahead aHi(S0); stage A(t+1,0)
#pragma unroll
        for (int m = 0; m < 4; ++m)
            aHi[m] = *(const bf16x8*)(S0 + aoff + (4 + m) * 1024);
        if (more) stageA(t + 1, 0, d0);
        __builtin_amdgcn_sched_barrier(0);
        __builtin_amdgcn_s_setprio(1);
#pragma unroll
        for (int m = 0; m < 4; ++m)
#pragma unroll
            for (int n = 0; n < 4; ++n)
                acc[m][n] = __builtin_amdgcn_mfma_f32_16x16x32_bf16(
                    aLo[m], bCur[n], acc[m][n], 0, 0, 0);
        __builtin_amdgcn_s_setprio(0);
        __builtin_amdgcn_sched_barrier(0);

        // ---- phase 1: publish S1(t); MFMA(aHi x bCur); read bNxt,aLo2(S1) --
        if (more) {
            asm volatile("s_waitcnt vmcnt(2)" ::: "memory");
        } else {
            asm volatile("s_waitcnt vmcnt(0)" ::: "memory");
        }
        __builtin_amdgcn_s_barrier();
        __builtin_amdgcn_sched_barrier(0);
#pragma unroll
        for (int n = 0; n < 4; ++n)
            bNxt[n] = *(const bf16x8*)(S1 + 16384 + boff + n * 1024);
#pragma unroll
        for (int m = 0; m < 4; ++m)
            aLo2[m] = *(const bf16x8*)(S1 + aoff + m * 1024);
        if (more) stageB(t + 1, 0, d0);
        __builtin_amdgcn_sched_barrier(0);
        __builtin_amdgcn_s_setprio(1);
#pragma unroll
        for (int m = 0; m < 4; ++m)
#pragma unroll
            for (int n = 0; n < 4; ++n)
                acc[4 + m][n] = __builtin_amdgcn_mfma_f32_16x16x32_bf16(
                    aHi[m], bCur[n], acc[4 + m][n], 0, 0, 0);
        __builtin_amdgcn_s_setprio(0);
        __builtin_amdgcn_sched_barrier(0);

        // ---- phase 2: MFMA(aLo2 x bNxt); read-ahead aHi2(S1); stage A(t+1,1)
#pragma unroll
        for (int m = 0; m < 4; ++m)
            aHi2[m] = *(const bf16x8*)(S1 + aoff + (4 + m) * 1024);
        if (more) stageA(t + 1, 1, d1);
        __builtin_amdgcn_sched_barrier(0);
        __builtin_amdgcn_s_setprio(1);
#pragma unroll
        for (int m = 0; m < 4; ++m)
#pragma unroll
            for (int n = 0; n < 4; ++n)
                acc[m][n] = __builtin_amdgcn_mfma_f32_16x16x32_bf16(
                    aLo2[m], bNxt[n], acc[m][n], 0, 0, 0);
        __builtin_amdgcn_s_setprio(0);
        __builtin_amdgcn_sched_barrier(0);

        // ---- phase 3: publish S0(t+1); MFMA(aHi2 x bNxt); read bCur,aLo ----
        if (more) {
            asm volatile("s_waitcnt vmcnt(2)" ::: "memory");
            __builtin_amdgcn_s_barrier();
            __builtin_amdgcn_sched_barrier(0);
#pragma unroll
            for (int n = 0; n < 4; ++n)
                bCur[n] = *(const bf16x8*)(Sn + 16384 + boff + n * 1024);
#pragma unroll
            for (int m = 0; m < 4; ++m)
                aLo[m] = *(const bf16x8*)(Sn + aoff + m * 1024);
            stageB(t + 1, 1, d1);
        }
        __builtin_amdgcn_sched_barrier(0);
        __builtin_amdgcn_s_setprio(1);
#pragma unroll
        for (int m = 0; m < 4; ++m)
#pragma unroll
            for (int n = 0; n < 4; ++n)
                acc[4 + m][n] = __builtin_amdgcn_mfma_f32_16x16x32_bf16(
                    aHi2[m], bNxt[n], acc[4 + m][n], 0, 0, 0);
        __builtin_amdgcn_s_setprio(0);
        __builtin_amdgcn_sched_barrier(0);
    }

    // epilogue: C/D map col = l&15, row = (l>>4)*4 + reg. NONTEMPORAL stores:
    // C is write-once; keep A/B panels resident in L3 instead.
#pragma unroll
    for (int m = 0; m < 8; ++m) {
        const int rowg = rowBase + wm * 128 + m * 16 + (l >> 4) * 4;
#pragma unroll
        for (int n = 0; n < 4; ++n) {
            const int colg = colBase + wn * 64 + n * 16 + (l & 15);
            float* cp = C + (size_t)rowg * DOUT + colg;
#pragma unroll
            for (int r = 0; r < 4; ++r)
                __builtin_nontemporal_store(acc[m][n][r], cp + (size_t)r * DOUT);
        }
    }
}

// ---------------------------------------------------------------------------
extern "C" void kernel_launch(void* const* d_in, const int* in_sizes, int n_in,
                              void* d_out, int out_size, void* d_ws, size_t ws_size,
                              hipStream_t stream) {
    const float* x      = (const float*)d_in[0];
    const int*   codes  = (const int*)d_in[1];
    const float* absmax = (const float*)d_in[2];
    const float* bias   = (const float*)d_in[3];
    const float* lora_A = (const float*)d_in[4];
    const float* lora_B = (const float*)d_in[5];
    float* out = (float*)d_out;

    unsigned short* xe = (unsigned short*)d_ws;        // [TOK][KE] bf16
    unsigned short* we = xe + (size_t)TOK * KE;        // [DOUT][KE] bf16

    prep_fused<<<PXB + DQB + TLB, 256, 0, stream>>>(x, lora_A, codes, absmax,
                                                    bias, lora_B, xe, we);
    gemm_bt<<<(TOK / BM) * (DOUT / BN), 512, 0, stream>>>(xe, we, out);
}

// Round 11
// 360.555 us; speedup vs baseline: 1.0375x; 1.0375x over previous
//
#include <hip/hip_runtime.h>
#include <hip/hip_bf16.h>
#include <cstdint>
#include <cstddef>

#define TOK   8192
#define DIN   4096
#define DOUT  4096
#define RANK  16
#define KE    4160   // DIN + 16 (loraB) + 1 (bias) + 47 pad -> 65 * 64
#define NKT64 (KE / 64)

#define BM 256
#define BN 256

// prep_fused block ranges
#define PXB 512                    // prep_x blocks
#define DQB 8192                   // dequant blocks
#define TLB 16                     // tail blocks

typedef __attribute__((ext_vector_type(8))) short bf16x8;
typedef __attribute__((ext_vector_type(4))) float f32x4;
typedef __attribute__((ext_vector_type(4))) int i32x4;
typedef __attribute__((ext_vector_type(8))) unsigned short u16x8;

__device__ __constant__ float NF4_CODE_D[16] = {
    -1.0f, -0.6961928009986877f, -0.5250730514526367f, -0.39491748809814453f,
    -0.28444138169288635f, -0.18477343022823334f, -0.09105003625154495f, 0.0f,
    0.07958029955625534f, 0.16093020141124725f, 0.24611230194568634f,
    0.33791524171829224f, 0.44070982933044434f, 0.5626170039176941f,
    0.7229568362236023f, 1.0f};

__device__ __forceinline__ unsigned short f2bf(float f) {
    union { float f; unsigned u; } v; v.f = f;
    unsigned u = v.u;
    unsigned r = (u + 0x7FFFu + ((u >> 16) & 1u)) >> 16;  // round-nearest-even
    return (unsigned short)r;
}

__device__ __forceinline__ void async_copy16(const void* g, void* l) {
    __builtin_amdgcn_global_load_lds(
        (const __attribute__((address_space(1))) void*)g,
        (__attribute__((address_space(3))) void*)l,
        16, 0, 0);
}

// ---------------------------------------------------------------------------
// Fused prep (R10-proven): x/codes nontemporal loads keep xe/we L3-resident.
// ---------------------------------------------------------------------------
__global__ __launch_bounds__(256) void prep_fused(
        const float* __restrict__ x, const float* __restrict__ lora_A,
        const int* __restrict__ codes, const float* __restrict__ absmax,
        const float* __restrict__ bias, const float* __restrict__ lora_B,
        unsigned short* __restrict__ xe, unsigned short* __restrict__ we) {
    __shared__ float tab[16];
    const int bid = blockIdx.x;
    const int tid = threadIdx.x;

    if (bid < PXB) {
        // ---- prep_x: wave handles 4 tokens; lane covers 8 consecutive k ----
        const int l = tid & 63;
        const int w = tid >> 6;
        const int t0 = bid * 16 + w * 4;

        float p[4][16];
#pragma unroll
        for (int a = 0; a < 4; ++a)
#pragma unroll
            for (int r = 0; r < 16; ++r) p[a][r] = 0.f;

        for (int it = 0; it < 8; ++it) {
            const int kb = it * 512 + l * 8;
            f32x4 xv[4][2];
#pragma unroll
            for (int a = 0; a < 4; ++a) {
                const f32x4* xp = (const f32x4*)(x + (size_t)(t0 + a) * DIN + kb);
                xv[a][0] = __builtin_nontemporal_load(xp);
                xv[a][1] = __builtin_nontemporal_load(xp + 1);
            }
#pragma unroll
            for (int a = 0; a < 4; ++a) {
                u16x8 s;
#pragma unroll
                for (int h = 0; h < 2; ++h) {
                    s[h * 4 + 0] = f2bf(xv[a][h].x);
                    s[h * 4 + 1] = f2bf(xv[a][h].y);
                    s[h * 4 + 2] = f2bf(xv[a][h].z);
                    s[h * 4 + 3] = f2bf(xv[a][h].w);
                }
                *(u16x8*)(xe + (size_t)(t0 + a) * KE + kb) = s;  // 16B store
            }
#pragma unroll
            for (int j = 0; j < 8; ++j) {
                const float4* ap = (const float4*)(lora_A + (size_t)(kb + j) * RANK);
                const float4 a0 = ap[0], a1 = ap[1], a2 = ap[2], a3 = ap[3];
                const float av[16] = {a0.x, a0.y, a0.z, a0.w, a1.x, a1.y, a1.z, a1.w,
                                      a2.x, a2.y, a2.z, a2.w, a3.x, a3.y, a3.z, a3.w};
#pragma unroll
                for (int a = 0; a < 4; ++a) {
                    const f32x4 xh = xv[a][j >> 2];
                    const float xs = (j & 3) == 0 ? xh.x : (j & 3) == 1 ? xh.y
                                   : (j & 3) == 2 ? xh.z : xh.w;
#pragma unroll
                    for (int r = 0; r < 16; ++r) p[a][r] += xs * av[r];
                }
            }
        }

#pragma unroll
        for (int a = 0; a < 4; ++a) {
#pragma unroll
            for (int r = 0; r < 16; ++r) {
                float v = p[a][r];
#pragma unroll
                for (int off = 32; off > 0; off >>= 1) v += __shfl_xor(v, off, 64);
                if (l == r)
                    xe[(size_t)(t0 + a) * KE + DIN + r] = f2bf(4.0f * v);  // SCALING=4
            }
            if (l >= 16)  // cols 4112..4159: bias-one then zeros
                xe[(size_t)(t0 + a) * KE + DIN + l] =
                    (l == 16) ? (unsigned short)0x3F80u : (unsigned short)0u;
        }
    } else if (bid < PXB + DQB) {
        // ---- dequant_w ----
        if (tid < 16) tab[tid] = NF4_CODE_D[tid];
        __syncthreads();
        const size_t t = (size_t)(bid - PXB) * 256 + tid;
        const size_t base = t * 8;
        const int o = (int)(base >> 12);          // / DIN
        const int k = (int)(base & (DIN - 1));
        const float am = absmax[base >> 6];
        const i32x4 c0 = __builtin_nontemporal_load((const i32x4*)(codes + base));
        const i32x4 c1 = __builtin_nontemporal_load((const i32x4*)(codes + base + 4));
        u16x8 ov;
        ov[0] = f2bf(tab[c0.x] * am);
        ov[1] = f2bf(tab[c0.y] * am);
        ov[2] = f2bf(tab[c0.z] * am);
        ov[3] = f2bf(tab[c0.w] * am);
        ov[4] = f2bf(tab[c1.x] * am);
        ov[5] = f2bf(tab[c1.y] * am);
        ov[6] = f2bf(tab[c1.z] * am);
        ov[7] = f2bf(tab[c1.w] * am);
        *(u16x8*)(we + (size_t)o * KE + k) = ov;
    } else {
        // ---- fill we tail ----
        const int o = (bid - PXB - DQB) * 256 + tid;
        unsigned short* dst = we + (size_t)o * KE + DIN;
#pragma unroll
        for (int r = 0; r < RANK; ++r) dst[r] = f2bf(lora_B[(size_t)r * DOUT + o]);
        dst[16] = f2bf(bias[o]);
#pragma unroll
        for (int r = 17; r < 64; ++r) dst[r] = 0;
    }
}

// ---------------------------------------------------------------------------
// Kernel 2: C[t,o] = sum_k A[t,k]*B[o,k]  (K-major bf16, K=KE)
// R11 = R4 schedule with stages shifted 2 PHASES EARLIER (deeper in-flight
// window, same 1-stage-per-phase stagger, same barriers/slots):
//   ph0(t): stage A(t+1,1)->d1   ph1(t): stage B(t+1,1)->d1
//   ph2(t): stage A(t+2,0)->e0   ph3(t): stage B(t+2,0)->e0
// Stage->publish distance: 5/4 phases (was 3/2) ~ covers HBM latency.
// vmcnt ledger (per wave; 2 loads per stage; in-order retirement):
//   ph1-top(t): outstanding {A(t,1),B(t,1),A(t+1,0),B(t+1,0),A(t+1,1)} = 10
//               -> vmcnt(6) retires A(t,1),B(t,1) = publishes S1(t)
//               (t = NKT-1: outstanding {A,B(t,1)} = 4 -> vmcnt(0))
//   ph3-top(t): outstanding {A(t+1,0),B(t+1,0),A(t+1,1),B(t+1,1)} = 8
//               -> vmcnt(4) retires A,B(t+1,0) = publishes S0(t+1)
// Prologue: stage S0(0),S1(0),S0(1) (12 loads) -> vmcnt(8) publishes S0(0).
// WAR: d1 = slot of S1(t-1) (readers' MFMA done by ph3(t-1), barrier
// between); e0 = slot of S0(t) (aHi consumed by ph1(t) MFMA, precedes ph2).
// ---------------------------------------------------------------------------
__global__ __launch_bounds__(512, 2) void gemm_bt(const unsigned short* __restrict__ A,
                                                  const unsigned short* __restrict__ B,
                                                  float* __restrict__ C) {
    __shared__ __attribute__((aligned(1024))) char smem[4 * 32768];  // 128 KiB

    const int tid = threadIdx.x;
    const int l = tid & 63;
    const int w = tid >> 6;
    const int wm = w >> 2;      // 0..1
    const int wn = w & 3;       // 0..3

    const int tm = blockIdx.x >> 4;     // 32 row tiles
    const int tn = blockIdx.x & 15;     // 16 col tiles
    const int rowBase = tm * BM;
    const int colBase = tn * BN;

    // staging coords (pre-swizzled global source; linear LDS dest)
    int srow[2], scolb[2], loffs[2];
#pragma unroll
    for (int g = 0; g < 2; ++g) {
        const int loff = g * 8192 + tid * 16;               // linear LDS byte
        const int soff = loff ^ (((loff >> 7) & 7) << 4);   // involution
        loffs[g] = loff;
        srow[g] = soff >> 6;          // row of [256][32] bf16 slice
        scolb[g] = soff & 63;         // byte within 64B row
    }

    auto stageA = [&](int tt, int kh, int slot) {
        char* dst = smem + slot * 32768;
        const int k0 = tt * 64 + kh * 32;
#pragma unroll
        for (int g = 0; g < 2; ++g)
            async_copy16((const char*)A + ((size_t)(rowBase + srow[g]) * KE + k0) * 2 + scolb[g],
                         dst + loffs[g]);
    };
    auto stageB = [&](int tt, int kh, int slot) {
        char* dst = smem + slot * 32768 + 16384;
        const int k0 = tt * 64 + kh * 32;
#pragma unroll
        for (int g = 0; g < 2; ++g)
            async_copy16((const char*)B + ((size_t)(colBase + srow[g]) * KE + k0) * 2 + scolb[g],
                         dst + loffs[g]);
    };

    // swizzled fragment read offsets (within a 16 KiB slice)
    const int lmask = ((l >> 1) & 7) << 4;
    const int aoff = (((wm * 128 + (l & 15)) * 64) + ((l >> 4) * 16)) ^ lmask;
    const int boff = (((wn * 64 + (l & 15)) * 64) + ((l >> 4) * 16)) ^ lmask;

    f32x4 acc[8][4];
#pragma unroll
    for (int m = 0; m < 8; ++m)
#pragma unroll
        for (int n = 0; n < 4; ++n) acc[m][n] = (f32x4){0.f, 0.f, 0.f, 0.f};

    bf16x8 aLo[4], aHi[4], aLo2[4], aHi2[4], bCur[4], bNxt[4];

    // prologue: S0(0)->slot0, S1(0)->slot1, S0(1)->slot2; publish S0(0)
    stageA(0, 0, 0); stageB(0, 0, 0);
    stageA(0, 1, 1); stageB(0, 1, 1);
    stageA(1, 0, 2); stageB(1, 0, 2);
    asm volatile("s_waitcnt vmcnt(8)" ::: "memory");
    __builtin_amdgcn_s_barrier();
    {
        const char* S0 = smem;  // slot 0
#pragma unroll
        for (int n = 0; n < 4; ++n)
            bCur[n] = *(const bf16x8*)(S0 + 16384 + boff + n * 1024);
#pragma unroll
        for (int m = 0; m < 4; ++m)
            aLo[m] = *(const bf16x8*)(S0 + aoff + m * 1024);
    }

    for (int t = 0; t < NKT64; ++t) {
        const char* S0 = smem + ((2 * t) & 3) * 32768;       // slice (t,k0)
        const char* S1 = smem + ((2 * t + 1) & 3) * 32768;   // slice (t,k1)
        const char* Sn = smem + ((2 * t + 2) & 3) * 32768;   // slice (t+1,k0)
        const int d1 = (2 * t + 3) & 3;    // slot for S1(t+1)
        const int e0 = (2 * t + 4) & 3;    // slot for S0(t+2) (= (2t)&3)
        const bool more = (t + 1 < NKT64);
        const bool more2 = (t + 2 < NKT64);

        // ---- phase 0: MFMA(aLo x bCur); read-ahead aHi(S0); stage A(t+1,1)
#pragma unroll
        for (int m = 0; m < 4; ++m)
            aHi[m] = *(const bf16x8*)(S0 + aoff + (4 + m) * 1024);
        if (more) stageA(t + 1, 1, d1);
        __builtin_amdgcn_sched_barrier(0);
        __builtin_amdgcn_s_setprio(1);
#pragma unroll
        for (int m = 0; m < 4; ++m)
#pragma unroll
            for (int n = 0; n < 4; ++n)
                acc[m][n] = __builtin_amdgcn_mfma_f32_16x16x32_bf16(
                    aLo[m], bCur[n], acc[m][n], 0, 0, 0);
        __builtin_amdgcn_s_setprio(0);
        __builtin_amdgcn_sched_barrier(0);

        // ---- phase 1: publish S1(t); MFMA(aHi x bCur); read bNxt,aLo2(S1) --
        if (more) {
            asm volatile("s_waitcnt vmcnt(6)" ::: "memory");
        } else {
            asm volatile("s_waitcnt vmcnt(0)" ::: "memory");
        }
        __builtin_amdgcn_s_barrier();
        __builtin_amdgcn_sched_barrier(0);
#pragma unroll
        for (int n = 0; n < 4; ++n)
            bNxt[n] = *(const bf16x8*)(S1 + 16384 + boff + n * 1024);
#pragma unroll
        for (int m = 0; m < 4; ++m)
            aLo2[m] = *(const bf16x8*)(S1 + aoff + m * 1024);
        if (more) stageB(t + 1, 1, d1);
        __builtin_amdgcn_sched_barrier(0);
        __builtin_amdgcn_s_setprio(1);
#pragma unroll
        for (int m = 0; m < 4; ++m)
#pragma unroll
            for (int n = 0; n < 4; ++n)
                acc[4 + m][n] = __builtin_amdgcn_mfma_f32_16x16x32_bf16(
                    aHi[m], bCur[n], acc[4 + m][n], 0, 0, 0);
        __builtin_amdgcn_s_setprio(0);
        __builtin_amdgcn_sched_barrier(0);

        // ---- phase 2: MFMA(aLo2 x bNxt); read-ahead aHi2(S1); stage A(t+2,0)
#pragma unroll
        for (int m = 0; m < 4; ++m)
            aHi2[m] = *(const bf16x8*)(S1 + aoff + (4 + m) * 1024);
        if (more2) stageA(t + 2, 0, e0);
        __builtin_amdgcn_sched_barrier(0);
        __builtin_amdgcn_s_setprio(1);
#pragma unroll
        for (int m = 0; m < 4; ++m)
#pragma unroll
            for (int n = 0; n < 4; ++n)
                acc[m][n] = __builtin_amdgcn_mfma_f32_16x16x32_bf16(
                    aLo2[m], bNxt[n], acc[m][n], 0, 0, 0);
        __builtin_amdgcn_s_setprio(0);
        __builtin_amdgcn_sched_barrier(0);

        // ---- phase 3: publish S0(t+1); MFMA(aHi2 x bNxt); read bCur,aLo ----
        if (more) {
            asm volatile("s_waitcnt vmcnt(4)" ::: "memory");
            __builtin_amdgcn_s_barrier();
            __builtin_amdgcn_sched_barrier(0);
#pragma unroll
            for (int n = 0; n < 4; ++n)
                bCur[n] = *(const bf16x8*)(Sn + 16384 + boff + n * 1024);
#pragma unroll
            for (int m = 0; m < 4; ++m)
                aLo[m] = *(const bf16x8*)(Sn + aoff + m * 1024);
            if (more2) stageB(t + 2, 0, e0);
        }
        __builtin_amdgcn_sched_barrier(0);
        __builtin_amdgcn_s_setprio(1);
#pragma unroll
        for (int m = 0; m < 4; ++m)
#pragma unroll
            for (int n = 0; n < 4; ++n)
                acc[4 + m][n] = __builtin_amdgcn_mfma_f32_16x16x32_bf16(
                    aHi2[m], bNxt[n], acc[4 + m][n], 0, 0, 0);
        __builtin_amdgcn_s_setprio(0);
        __builtin_amdgcn_sched_barrier(0);
    }

    // epilogue: C/D map col = l&15, row = (l>>4)*4 + reg (plain stores —
    // R10 showed nontemporal stores raise HBM WRITE_SIZE 133->160 MB)
#pragma unroll
    for (int m = 0; m < 8; ++m) {
        const int rowg = rowBase + wm * 128 + m * 16 + (l >> 4) * 4;
#pragma unroll
        for (int n = 0; n < 4; ++n) {
            const int colg = colBase + wn * 64 + n * 16 + (l & 15);
            float* cp = C + (size_t)rowg * DOUT + colg;
#pragma unroll
            for (int r = 0; r < 4; ++r) cp[(size_t)r * DOUT] = acc[m][n][r];
        }
    }
}

// ---------------------------------------------------------------------------
extern "C" void kernel_launch(void* const* d_in, const int* in_sizes, int n_in,
                              void* d_out, int out_size, void* d_ws, size_t ws_size,
                              hipStream_t stream) {
    const float* x      = (const float*)d_in[0];
    const int*   codes  = (const int*)d_in[1];
    const float* absmax = (const float*)d_in[2];
    const float* bias   = (const float*)d_in[3];
    const float* lora_A = (const float*)d_in[4];
    const float* lora_B = (const float*)d_in[5];
    float* out = (float*)d_out;

    unsigned short* xe = (unsigned short*)d_ws;        // [TOK][KE] bf16
    unsigned short* we = xe + (size_t)TOK * KE;        // [DOUT][KE] bf16

    prep_fused<<<PXB + DQB + TLB, 256, 0, stream>>>(x, lora_A, codes, absmax,
                                                    bias, lora_B, xe, we);
    gemm_bt<<<(TOK / BM) * (DOUT / BN), 512, 0, stream>>>(xe, we, out);
}